// Round 1
// baseline (481.095 us; speedup 1.0000x reference)
//
#include <hip/hip_runtime.h>
#include <hip/hip_bf16.h>

// DecoderLSTM: B=256, S=512, H=512, E=256, V=16000
#define B_ 256
#define S_ 512
#define H_ 512
#define E_ 256
#define V_ 16000

typedef __attribute__((ext_vector_type(4))) float f32x4_t;
typedef __attribute__((ext_vector_type(8))) short bf16x8_t;

__device__ __forceinline__ short f2bf(float f) {
    union { float f; unsigned u; } v; v.f = f;
    unsigned r = v.u + 0x7fffu + ((v.u >> 16) & 1u);   // RNE
    return (short)(r >> 16);
}

// load 8 f32 from global, convert, store 8 bf16 (16B) to LDS
__device__ __forceinline__ void cvt8(short* dst, const float* src) {
    f32x4_t a = *(const f32x4_t*)src;
    f32x4_t b = *(const f32x4_t*)(src + 4);
    bf16x8_t o;
    o[0] = f2bf(a[0]); o[1] = f2bf(a[1]); o[2] = f2bf(a[2]); o[3] = f2bf(a[3]);
    o[4] = f2bf(b[0]); o[5] = f2bf(b[1]); o[6] = f2bf(b[2]); o[7] = f2bf(b[3]);
    *(bf16x8_t*)dst = o;
}

__device__ __forceinline__ float fast_tanh(float x) {
    float xc = fminf(8.f, fmaxf(-8.f, x));
    float e = __expf(2.f * xc);
    return (e - 1.f) / (e + 1.f);
}

// ---------------------------------------------------------------------------
// gemm_bigN: BM=128, BN=512 (full H in-block), BK=32, 8 waves (512 thr).
// Wave w: wm=w>>2 (2 M-halves of 64 rows), wn=w&3 (4 col-blocks of 128).
// A is f32 (converted inline). B = attn_W columns (row stride 2H), offset by KIND.
// KIND 0: out[row][col] = acc + attn_b[col]            (bias1 = h@W1^T + b)
// KIND 1: scores[row] = sum_col v[col]*tanh(acc + bias1[b][col])
// ---------------------------------------------------------------------------
template<int KIND>
__global__ __launch_bounds__(512, 1)
void gemm_bigN(const float* __restrict__ A,
               const float* __restrict__ Wfull,
               const float* __restrict__ biasvec,   // KIND0: attn_b[512], KIND1: bias1[256][512]
               const float* __restrict__ vvec,      // KIND1: v[512]
               float* __restrict__ out)
{
    __shared__ short As[128 * 40];
    __shared__ short Bs[512 * 40];
    __shared__ float bias_s[512];
    __shared__ float v_s[512];
    __shared__ float red[128][4];

    const int t    = threadIdx.x;
    const int lane = t & 63;
    const int w    = t >> 6;
    const int wm   = w >> 2;
    const int wn   = w & 3;
    const int row0 = blockIdx.x * 128;

    if constexpr (KIND == 0) {
        bias_s[t] = biasvec[t];                       // attn_b
    } else {
        const int b = row0 >> 9;                      // 4 blocks per batch row
        bias_s[t] = biasvec[b * H_ + t];              // bias1[b][:]
        v_s[t]    = vvec[t];
    }

    f32x4_t acc[4][8];
#pragma unroll
    for (int i = 0; i < 4; ++i)
#pragma unroll
        for (int j = 0; j < 8; ++j)
            acc[i][j] = (f32x4_t){0.f, 0.f, 0.f, 0.f};

    const int arow = t >> 2;                 // 0..127
    const int akc  = (t & 3) * 8;            // 0,8,16,24
    const float* aptr = A + (size_t)(row0 + arow) * H_ + akc;

    const int bcol = t;                      // 0..511
    const float* bptr = Wfull + (size_t)bcol * (2 * H_) + (KIND == 1 ? H_ : 0);

    for (int ks = 0; ks < H_ / 32; ++ks) {
        const int k0 = ks * 32;
        __syncthreads();
        cvt8(&As[arow * 40 + akc], aptr + k0);
        cvt8(&Bs[bcol * 40 + 0],  bptr + k0 + 0);
        cvt8(&Bs[bcol * 40 + 8],  bptr + k0 + 8);
        cvt8(&Bs[bcol * 40 + 16], bptr + k0 + 16);
        cvt8(&Bs[bcol * 40 + 24], bptr + k0 + 24);
        __syncthreads();

        bf16x8_t af[4], bfr[8];
        const int ka = (lane >> 4) * 8;
#pragma unroll
        for (int mf = 0; mf < 4; ++mf)
            af[mf] = *(const bf16x8_t*)&As[(wm * 64 + mf * 16 + (lane & 15)) * 40 + ka];
#pragma unroll
        for (int nf = 0; nf < 8; ++nf)
            bfr[nf] = *(const bf16x8_t*)&Bs[(wn * 128 + nf * 16 + (lane & 15)) * 40 + ka];
#pragma unroll
        for (int mf = 0; mf < 4; ++mf)
#pragma unroll
            for (int nf = 0; nf < 8; ++nf)
                acc[mf][nf] = __builtin_amdgcn_mfma_f32_16x16x32_bf16(
                    af[mf], bfr[nf], acc[mf][nf], 0, 0, 0);
    }

    if constexpr (KIND == 0) {
#pragma unroll
        for (int mf = 0; mf < 4; ++mf)
#pragma unroll
            for (int nf = 0; nf < 8; ++nf) {
                const int col  = wn * 128 + nf * 16 + (lane & 15);
                const int rowb = wm * 64 + mf * 16 + ((lane >> 4) << 2);
                const float bb = bias_s[col];
#pragma unroll
                for (int r = 0; r < 4; ++r)
                    out[(size_t)(row0 + rowb + r) * H_ + col] = acc[mf][nf][r] + bb;
            }
    } else {
        float part[16];
#pragma unroll
        for (int i = 0; i < 16; ++i) part[i] = 0.f;
#pragma unroll
        for (int nf = 0; nf < 8; ++nf) {
            const int col = wn * 128 + nf * 16 + (lane & 15);
            const float bb = bias_s[col];
            const float vvl = v_s[col];
#pragma unroll
            for (int mf = 0; mf < 4; ++mf)
#pragma unroll
                for (int r = 0; r < 4; ++r)
                    part[mf * 4 + r] += vvl * fast_tanh(acc[mf][nf][r] + bb);
        }
#pragma unroll
        for (int i = 0; i < 16; ++i) {
            float p = part[i];
            p += __shfl_xor(p, 1);
            p += __shfl_xor(p, 2);
            p += __shfl_xor(p, 4);
            p += __shfl_xor(p, 8);
            part[i] = p;
        }
        if ((lane & 15) == 0) {
#pragma unroll
            for (int mf = 0; mf < 4; ++mf)
#pragma unroll
                for (int r = 0; r < 4; ++r)
                    red[wm * 64 + mf * 16 + ((lane >> 4) << 2) + r][wn] = part[mf * 4 + r];
        }
        __syncthreads();
        if (t < 128)
            out[row0 + t] = red[t][0] + red[t][1] + red[t][2] + red[t][3];
    }
}

// ---------------------------------------------------------------------------
// gemm_std: BM=128, BN=128, BK=32, 4 waves (256 thr). A is pre-converted bf16.
// KIND 0 (gates): K=1280, N=2048, B = [W_ih | W_hh] rows, bias = b_ih+b_hh
// KIND 1 (pred):  K=512,  N=16000, B = fc_W rows,        bias = fc_b
// ---------------------------------------------------------------------------
template<int KIND>
__global__ __launch_bounds__(256, 2)
void gemm_std(const short* __restrict__ Abf,
              const float* __restrict__ B0,
              const float* __restrict__ B1,
              const float* __restrict__ bias0,
              const float* __restrict__ bias1v,
              float* __restrict__ out)
{
    constexpr int K = (KIND == 0) ? 1280 : 512;
    constexpr int N = (KIND == 0) ? 2048 : 16000;

    __shared__ short As[128 * 40];
    __shared__ short Bs[128 * 40];

    const int t    = threadIdx.x;
    const int lane = t & 63;
    const int w    = t >> 6;
    const int wm   = w >> 1;
    const int wn   = w & 1;
    const int row0 = blockIdx.x * 128;
    const int col0 = blockIdx.y * 128;

    f32x4_t acc[4][4];
#pragma unroll
    for (int i = 0; i < 4; ++i)
#pragma unroll
        for (int j = 0; j < 4; ++j)
            acc[i][j] = (f32x4_t){0.f, 0.f, 0.f, 0.f};

    const int arow = t >> 1, ah = (t & 1) * 16;
    const int bcol = t >> 1, bh = (t & 1) * 16;

    for (int ks = 0; ks < K / 32; ++ks) {
        const int k0 = ks * 32;
        __syncthreads();
        // A tile: already bf16
        const short* asrc = Abf + (size_t)(row0 + arow) * K + k0 + ah;
        *(bf16x8_t*)&As[arow * 40 + ah]     = *(const bf16x8_t*)asrc;
        *(bf16x8_t*)&As[arow * 40 + ah + 8] = *(const bf16x8_t*)(asrc + 8);
        // B tile: f32 -> bf16
        const float* bsrc;
        if constexpr (KIND == 0) {
            const int cg = col0 + bcol;
            bsrc = (k0 < 768) ? (B0 + (size_t)cg * 768 + k0 + bh)
                              : (B1 + (size_t)cg * 512 + (k0 - 768) + bh);
        } else {
            bsrc = B0 + (size_t)(col0 + bcol) * 512 + k0 + bh;
        }
        cvt8(&Bs[bcol * 40 + bh],     bsrc);
        cvt8(&Bs[bcol * 40 + bh + 8], bsrc + 8);
        __syncthreads();

        bf16x8_t af[4], bfr[4];
        const int ka = (lane >> 4) * 8;
#pragma unroll
        for (int mf = 0; mf < 4; ++mf)
            af[mf] = *(const bf16x8_t*)&As[(wm * 64 + mf * 16 + (lane & 15)) * 40 + ka];
#pragma unroll
        for (int nf = 0; nf < 4; ++nf)
            bfr[nf] = *(const bf16x8_t*)&Bs[(wn * 64 + nf * 16 + (lane & 15)) * 40 + ka];
#pragma unroll
        for (int mf = 0; mf < 4; ++mf)
#pragma unroll
            for (int nf = 0; nf < 4; ++nf)
                acc[mf][nf] = __builtin_amdgcn_mfma_f32_16x16x32_bf16(
                    af[mf], bfr[nf], acc[mf][nf], 0, 0, 0);
    }

#pragma unroll
    for (int mf = 0; mf < 4; ++mf)
#pragma unroll
        for (int nf = 0; nf < 4; ++nf) {
            const int col  = col0 + wn * 64 + nf * 16 + (lane & 15);
            const int rowb = row0 + wm * 64 + mf * 16 + ((lane >> 4) << 2);
            float bb;
            if constexpr (KIND == 0) bb = bias0[col] + bias1v[col];
            else                     bb = bias0[col];
#pragma unroll
            for (int r = 0; r < 4; ++r)
                out[(size_t)(rowb + r) * N + col] = acc[mf][nf][r] + bb;
        }
}

// ---------------------------------------------------------------------------
// small kernels
// ---------------------------------------------------------------------------
__global__ void prep_kernel(const int* __restrict__ tgt,
                            const float* __restrict__ emb,
                            const float* __restrict__ hidden,
                            short* __restrict__ x_cat)
{
    const int b = blockIdx.x, t = threadIdx.x;          // 256 threads
    const int tok = tgt[b];
    x_cat[(size_t)b * 1280 + t]             = f2bf(emb[(size_t)tok * E_ + t]);
    x_cat[(size_t)b * 1280 + 768 + t]       = f2bf(hidden[(size_t)b * H_ + t]);
    x_cat[(size_t)b * 1280 + 768 + 256 + t] = f2bf(hidden[(size_t)b * H_ + 256 + t]);
}

__global__ void softmax_kernel(const float* __restrict__ scores,
                               float* __restrict__ attn,
                               float* __restrict__ attn_out)
{
    const int b = blockIdx.x, t = threadIdx.x;          // 512 threads
    const int lane = t & 63, w = t >> 6;
    __shared__ float wred[8];
    const float val = scores[(size_t)b * S_ + t];
    float m = val;
#pragma unroll
    for (int off = 32; off; off >>= 1) m = fmaxf(m, __shfl_xor(m, off));
    if (lane == 0) wred[w] = m;
    __syncthreads();
    m = wred[0];
#pragma unroll
    for (int i = 1; i < 8; ++i) m = fmaxf(m, wred[i]);
    const float e = __expf(val - m);
    __syncthreads();
    float s = e;
#pragma unroll
    for (int off = 32; off; off >>= 1) s += __shfl_xor(s, off);
    if (lane == 0) wred[w] = s;
    __syncthreads();
    s = wred[0];
#pragma unroll
    for (int i = 1; i < 8; ++i) s += wred[i];
    const float a = e / s;
    attn[(size_t)b * S_ + t]     = a;
    attn_out[(size_t)b * S_ + t] = a;
}

__global__ void context_kernel(const float* __restrict__ attn,
                               const float* __restrict__ enc,
                               short* __restrict__ x_cat)
{
    const int b = blockIdx.x, t = threadIdx.x;          // 512 threads, one h each
    __shared__ float a_s[512];
    a_s[t] = attn[(size_t)b * S_ + t];
    __syncthreads();
    const float* ep = enc + (size_t)b * S_ * H_ + t;
    float acc0 = 0.f, acc1 = 0.f, acc2 = 0.f, acc3 = 0.f;
    for (int s = 0; s < 512; s += 8) {
        const float l0 = ep[(size_t)(s + 0) * H_];
        const float l1 = ep[(size_t)(s + 1) * H_];
        const float l2 = ep[(size_t)(s + 2) * H_];
        const float l3 = ep[(size_t)(s + 3) * H_];
        const float l4 = ep[(size_t)(s + 4) * H_];
        const float l5 = ep[(size_t)(s + 5) * H_];
        const float l6 = ep[(size_t)(s + 6) * H_];
        const float l7 = ep[(size_t)(s + 7) * H_];
        acc0 = fmaf(a_s[s + 0], l0, acc0);
        acc1 = fmaf(a_s[s + 1], l1, acc1);
        acc2 = fmaf(a_s[s + 2], l2, acc2);
        acc3 = fmaf(a_s[s + 3], l3, acc3);
        acc0 = fmaf(a_s[s + 4], l4, acc0);
        acc1 = fmaf(a_s[s + 5], l5, acc1);
        acc2 = fmaf(a_s[s + 6], l6, acc2);
        acc3 = fmaf(a_s[s + 7], l7, acc3);
    }
    x_cat[(size_t)b * 1280 + 256 + t] = f2bf((acc0 + acc1) + (acc2 + acc3));
}

__global__ void lstm_kernel(const float* __restrict__ gates,
                            const float* __restrict__ cell,
                            float* __restrict__ out_h,
                            float* __restrict__ out_c,
                            short* __restrict__ h_bf)
{
    const int b = blockIdx.x, t = threadIdx.x;          // 512 threads
    const float* g = gates + (size_t)b * 2048;
    const float gi = g[t], gf = g[512 + t], gg = g[1024 + t], go = g[1536 + t];
    const float c  = cell[(size_t)b * H_ + t];
    const float si = 1.f / (1.f + __expf(-gi));
    const float sf = 1.f / (1.f + __expf(-gf));
    const float so = 1.f / (1.f + __expf(-go));
    const float cn = sf * c + si * tanhf(gg);
    const float hn = so * tanhf(cn);
    out_h[(size_t)b * H_ + t] = hn;
    out_c[(size_t)b * H_ + t] = cn;
    h_bf[(size_t)b * H_ + t]  = f2bf(hn);
}

// ---------------------------------------------------------------------------
extern "C" void kernel_launch(void* const* d_in, const int* in_sizes, int n_in,
                              void* d_out, int out_size, void* d_ws, size_t ws_size,
                              hipStream_t stream)
{
    (void)in_sizes; (void)n_in; (void)out_size; (void)ws_size;

    const int*   tgt    = (const int*)d_in[0];
    const float* hidden = (const float*)d_in[1];
    const float* cell   = (const float*)d_in[2];
    const float* enc    = (const float*)d_in[3];
    const float* emb    = (const float*)d_in[4];
    const float* attn_W = (const float*)d_in[5];
    const float* attn_b = (const float*)d_in[6];
    const float* vv     = (const float*)d_in[7];
    const float* W_ih   = (const float*)d_in[8];
    const float* W_hh   = (const float*)d_in[9];
    const float* b_ih   = (const float*)d_in[10];
    const float* b_hh   = (const float*)d_in[11];
    const float* fc_W   = (const float*)d_in[12];
    const float* fc_b   = (const float*)d_in[13];

    float* out_pred = (float*)d_out;                       // [256][16000]
    float* out_h    = out_pred + (size_t)B_ * V_;          // [256][512]
    float* out_c    = out_h + (size_t)B_ * H_;             // [256][512]
    float* out_attn = out_c + (size_t)B_ * H_;             // [256][512]

    char*  ws     = (char*)d_ws;
    float* bias1  = (float*)ws;                            // 256*512 f32
    float* scores = bias1 + (size_t)B_ * H_;               // 256*512 f32 (B*S flat)
    float* attn   = scores + (size_t)B_ * S_;              // 256*512 f32
    float* gates  = attn + (size_t)B_ * S_;                // 256*2048 f32
    short* x_cat  = (short*)(gates + (size_t)B_ * 2048);   // 256*1280 bf16
    short* h_bf   = x_cat + (size_t)B_ * 1280;             // 256*512 bf16

    // 1. embedding gather + h into x_cat (bf16)
    prep_kernel<<<B_, 256, 0, stream>>>(tgt, emb, hidden, x_cat);
    // 2. bias1 = h @ W1^T + attn_b    (s-invariant part of the energy)
    gemm_bigN<0><<<2, 512, 0, stream>>>(hidden, attn_W, attn_b, nullptr, bias1);
    // 3. scores[b,s] = v . tanh(enc @ W2^T + bias1[b])
    gemm_bigN<1><<<(B_ * S_) / 128, 512, 0, stream>>>(enc, attn_W, bias1, vv, scores);
    // 4. softmax over s
    softmax_kernel<<<B_, 512, 0, stream>>>(scores, attn, out_attn);
    // 5. context = attn-weighted enc sum -> x_cat[:,256:768] (bf16)
    context_kernel<<<B_, 512, 0, stream>>>(attn, enc, x_cat);
    // 6. gates = x_cat @ [W_ih|W_hh]^T + b_ih + b_hh
    gemm_std<0><<<dim3(2, 16), 256, 0, stream>>>(x_cat, W_ih, W_hh, b_ih, b_hh, gates);
    // 7. LSTM pointwise -> h_new, c_new outputs + h_new bf16
    lstm_kernel<<<B_, 512, 0, stream>>>(gates, cell, out_h, out_c, h_bf);
    // 8. prediction = h_new @ fc_W^T + fc_b
    gemm_std<1><<<dim3(2, 125), 256, 0, stream>>>(h_bf, fc_W, nullptr, fc_b, nullptr, out_pred);
}

// Round 2
// 310.316 us; speedup vs baseline: 1.5503x; 1.5503x over previous
//
#include <hip/hip_runtime.h>
#include <hip/hip_bf16.h>

// DecoderLSTM: B=256, S=512, H=512, E=256, V=16000
#define B_ 256
#define S_ 512
#define H_ 512
#define E_ 256
#define V_ 16000

typedef __attribute__((ext_vector_type(4))) float f32x4_t;
typedef __attribute__((ext_vector_type(8))) short bf16x8_t;

__device__ __forceinline__ short f2bf(float f) {
    union { float f; unsigned u; } v; v.f = f;
    unsigned r = v.u + 0x7fffu + ((v.u >> 16) & 1u);   // RNE
    return (short)(r >> 16);
}

__device__ __forceinline__ void cvt8(short* dst, const float* src) {
    f32x4_t a = *(const f32x4_t*)src;
    f32x4_t b = *(const f32x4_t*)(src + 4);
    bf16x8_t o;
    o[0] = f2bf(a[0]); o[1] = f2bf(a[1]); o[2] = f2bf(a[2]); o[3] = f2bf(a[3]);
    o[4] = f2bf(b[0]); o[5] = f2bf(b[1]); o[6] = f2bf(b[2]); o[7] = f2bf(b[3]);
    *(bf16x8_t*)dst = o;
}

__device__ __forceinline__ bf16x8_t pack8(f32x4_t a, f32x4_t b) {
    bf16x8_t o;
    o[0] = f2bf(a[0]); o[1] = f2bf(a[1]); o[2] = f2bf(a[2]); o[3] = f2bf(a[3]);
    o[4] = f2bf(b[0]); o[5] = f2bf(b[1]); o[6] = f2bf(b[2]); o[7] = f2bf(b[3]);
    return o;
}

__device__ __forceinline__ float fast_tanh(float x) {
    float xc = fminf(8.f, fmaxf(-8.f, x));
    float e = __expf(2.f * xc);
    return (e - 1.f) / (e + 1.f);
}

// ---------------------------------------------------------------------------
// pack_w2: attn_W second half (W2) -> fragment-ordered bf16.
// chunk c = ((k32*4 + g)*8 + nf)*64 + lane holds 8 bf16:
//   W2[col = g*128+nf*16+(lane&15)][k = k32*32+(lane>>4)*8 + j]
// ---------------------------------------------------------------------------
__global__ void pack_w2(const float* __restrict__ attn_W, short* __restrict__ Bp)
{
    const int c    = blockIdx.x * 256 + threadIdx.x;       // 32768 chunks
    const int lane = c & 63;
    const int nf   = (c >> 6) & 7;
    const int g    = (c >> 9) & 3;
    const int k32  = c >> 11;
    const int col  = g * 128 + nf * 16 + (lane & 15);
    const int k    = k32 * 32 + (lane >> 4) * 8;
    cvt8(Bp + (size_t)c * 8, attn_W + (size_t)col * (2 * H_) + H_ + k);
}

// ---------------------------------------------------------------------------
// bias1: h @ W1^T + attn_b.  128 blocks x 512 thr, 2 batches per block.
// ---------------------------------------------------------------------------
__global__ void bias1_kernel(const float* __restrict__ hidden,
                             const float* __restrict__ attn_W,
                             const float* __restrict__ attn_b,
                             float* __restrict__ bias1)
{
    const int t  = threadIdx.x;                // output col
    const int b0 = blockIdx.x * 2;
    __shared__ float h_s[2][512];
    h_s[0][t] = hidden[(size_t)b0 * H_ + t];
    h_s[1][t] = hidden[(size_t)(b0 + 1) * H_ + t];
    __syncthreads();
    const float* wrow = attn_W + (size_t)t * (2 * H_);     // W1 part: cols 0..511
    float a0 = 0.f, a1 = 0.f;
#pragma unroll 4
    for (int k = 0; k < 512; k += 4) {
        f32x4_t wv = *(const f32x4_t*)(wrow + k);
        a0 = fmaf(wv[0], h_s[0][k],     a0);
        a0 = fmaf(wv[1], h_s[0][k + 1], a0);
        a0 = fmaf(wv[2], h_s[0][k + 2], a0);
        a0 = fmaf(wv[3], h_s[0][k + 3], a0);
        a1 = fmaf(wv[0], h_s[1][k],     a1);
        a1 = fmaf(wv[1], h_s[1][k + 1], a1);
        a1 = fmaf(wv[2], h_s[1][k + 2], a1);
        a1 = fmaf(wv[3], h_s[1][k + 3], a1);
    }
    const float bb = attn_b[t];
    bias1[(size_t)b0 * H_ + t]       = a0 + bb;
    bias1[(size_t)(b0 + 1) * H_ + t] = a1 + bb;
}

// ---------------------------------------------------------------------------
// scores_gemm: BM=128, BN=512 (full), BK=64, 8 waves.
// A = enc f32, reg-staged -> cvt -> XOR-swizzled LDS (double-buffered).
// B = fragment-ordered prepacked bf16, global->reg, coalesced, no LDS.
// out[row] = sum_col v[col]*tanh(acc + bias1[b][col])
// ---------------------------------------------------------------------------
__global__ __launch_bounds__(512, 2)
void scores_gemm(const float* __restrict__ enc,
                 const short* __restrict__ Bp,
                 const float* __restrict__ bias1,
                 const float* __restrict__ vvec,
                 float* __restrict__ out)
{
    __shared__ short As[2][128 * 64];
    __shared__ float bias_s[512];
    __shared__ float v_s[512];
    __shared__ float red[128][4];

    const int t    = threadIdx.x;
    const int lane = t & 63;
    const int w    = t >> 6;
    const int wm   = w >> 2;          // 0..1  (64-row half)
    const int wn   = w & 3;           // 0..3  (128-col block)
    const int row0 = blockIdx.x * 128;

    bias_s[t] = bias1[(size_t)(row0 >> 9) * H_ + t];
    v_s[t]    = vvec[t];

    // A staging: thread t -> row ar, 16-col quarter aq (two 16B slots)
    const int ar = t >> 2, aq = t & 3;
    const float* aptr = enc + (size_t)(row0 + ar) * H_ + aq * 16;
    const int ws0 = ar * 64 + (((aq * 2 + 0) ^ (ar & 7)) * 8);
    const int ws1 = ar * 64 + (((aq * 2 + 1) ^ (ar & 7)) * 8);

    f32x4_t acc[4][8];
#pragma unroll
    for (int i = 0; i < 4; ++i)
#pragma unroll
        for (int j = 0; j < 8; ++j)
            acc[i][j] = (f32x4_t){0.f, 0.f, 0.f, 0.f};

    // prologue: stage K-step 0
    {
        f32x4_t v0 = *(const f32x4_t*)(aptr + 0);
        f32x4_t v1 = *(const f32x4_t*)(aptr + 4);
        f32x4_t v2 = *(const f32x4_t*)(aptr + 8);
        f32x4_t v3 = *(const f32x4_t*)(aptr + 12);
        *(bf16x8_t*)&As[0][ws0] = pack8(v0, v1);
        *(bf16x8_t*)&As[0][ws1] = pack8(v2, v3);
    }
    __syncthreads();

    int cur = 0;
    for (int ks = 0; ks < 8; ++ks) {
        // B fragments for this K-step (k32 = 2ks, 2ks+1), coalesced 16B/lane
        const short* bb = Bp + ((size_t)(((2 * ks) * 4 + wn) * 8) * 64 + lane) * 8;
        bf16x8_t bA[8], bB[8];
#pragma unroll
        for (int nf = 0; nf < 8; ++nf) bA[nf] = *(const bf16x8_t*)(bb + nf * 512);
#pragma unroll
        for (int nf = 0; nf < 8; ++nf) bB[nf] = *(const bf16x8_t*)(bb + 16384 + nf * 512);

        // prefetch next A tile (f32, in-flight across the MFMAs)
        f32x4_t n0, n1, n2, n3;
        if (ks < 7) {
            const float* ap = aptr + (ks + 1) * 64;
            n0 = *(const f32x4_t*)(ap + 0);
            n1 = *(const f32x4_t*)(ap + 4);
            n2 = *(const f32x4_t*)(ap + 8);
            n3 = *(const f32x4_t*)(ap + 12);
        }

        // A fragments from swizzled LDS
        bf16x8_t af0[4], af1[4];
#pragma unroll
        for (int mf = 0; mf < 4; ++mf) {
            const int r = wm * 64 + mf * 16 + (lane & 15);
            af0[mf] = *(const bf16x8_t*)&As[cur][r * 64 + ((((lane >> 4))     ^ (r & 7)) * 8)];
            af1[mf] = *(const bf16x8_t*)&As[cur][r * 64 + (((4 + (lane >> 4)) ^ (r & 7)) * 8)];
        }

#pragma unroll
        for (int mf = 0; mf < 4; ++mf)
#pragma unroll
            for (int nf = 0; nf < 8; ++nf)
                acc[mf][nf] = __builtin_amdgcn_mfma_f32_16x16x32_bf16(
                    af0[mf], bA[nf], acc[mf][nf], 0, 0, 0);
#pragma unroll
        for (int mf = 0; mf < 4; ++mf)
#pragma unroll
            for (int nf = 0; nf < 8; ++nf)
                acc[mf][nf] = __builtin_amdgcn_mfma_f32_16x16x32_bf16(
                    af1[mf], bB[nf], acc[mf][nf], 0, 0, 0);

        if (ks < 7) {
            *(bf16x8_t*)&As[cur ^ 1][ws0] = pack8(n0, n1);
            *(bf16x8_t*)&As[cur ^ 1][ws1] = pack8(n2, n3);
        }
        __syncthreads();
        cur ^= 1;
    }

    // epilogue: scores = sum_col v*tanh(acc + bias1)
    float part[16];
#pragma unroll
    for (int i = 0; i < 16; ++i) part[i] = 0.f;
#pragma unroll
    for (int nf = 0; nf < 8; ++nf) {
        const int col  = wn * 128 + nf * 16 + (lane & 15);
        const float bb = bias_s[col];
        const float vl = v_s[col];
#pragma unroll
        for (int mf = 0; mf < 4; ++mf)
#pragma unroll
            for (int r = 0; r < 4; ++r)
                part[mf * 4 + r] += vl * fast_tanh(acc[mf][nf][r] + bb);
    }
#pragma unroll
    for (int i = 0; i < 16; ++i) {
        float p = part[i];
        p += __shfl_xor(p, 1);
        p += __shfl_xor(p, 2);
        p += __shfl_xor(p, 4);
        p += __shfl_xor(p, 8);
        part[i] = p;
    }
    if ((lane & 15) == 0) {
#pragma unroll
        for (int mf = 0; mf < 4; ++mf)
#pragma unroll
            for (int r = 0; r < 4; ++r)
                red[wm * 64 + mf * 16 + ((lane >> 4) << 2) + r][wn] = part[mf * 4 + r];
    }
    __syncthreads();
    if (t < 128)
        out[row0 + t] = red[t][0] + red[t][1] + red[t][2] + red[t][3];
}

// ---------------------------------------------------------------------------
// gemm_std: BM=128, BN=128, BK=32, 4 waves (256 thr). A is pre-converted bf16.
// KIND 0 (gates): K=1280, N=2048, B = [W_ih | W_hh] rows, bias = b_ih+b_hh
// KIND 1 (pred):  K=512,  N=16000, B = fc_W rows,        bias = fc_b
// ---------------------------------------------------------------------------
template<int KIND>
__global__ __launch_bounds__(256, 2)
void gemm_std(const short* __restrict__ Abf,
              const float* __restrict__ B0,
              const float* __restrict__ B1,
              const float* __restrict__ bias0,
              const float* __restrict__ bias1v,
              float* __restrict__ out)
{
    constexpr int K = (KIND == 0) ? 1280 : 512;
    constexpr int N = (KIND == 0) ? 2048 : 16000;

    __shared__ short As[128 * 40];
    __shared__ short Bs[128 * 40];

    const int t    = threadIdx.x;
    const int lane = t & 63;
    const int w    = t >> 6;
    const int wm   = w >> 1;
    const int wn   = w & 1;
    const int row0 = blockIdx.x * 128;
    const int col0 = blockIdx.y * 128;

    f32x4_t acc[4][4];
#pragma unroll
    for (int i = 0; i < 4; ++i)
#pragma unroll
        for (int j = 0; j < 4; ++j)
            acc[i][j] = (f32x4_t){0.f, 0.f, 0.f, 0.f};

    const int arow = t >> 1, ah = (t & 1) * 16;
    const int bcol = t >> 1, bh = (t & 1) * 16;

    for (int ks = 0; ks < K / 32; ++ks) {
        const int k0 = ks * 32;
        __syncthreads();
        const short* asrc = Abf + (size_t)(row0 + arow) * K + k0 + ah;
        *(bf16x8_t*)&As[arow * 40 + ah]     = *(const bf16x8_t*)asrc;
        *(bf16x8_t*)&As[arow * 40 + ah + 8] = *(const bf16x8_t*)(asrc + 8);
        const float* bsrc;
        if constexpr (KIND == 0) {
            const int cg = col0 + bcol;
            bsrc = (k0 < 768) ? (B0 + (size_t)cg * 768 + k0 + bh)
                              : (B1 + (size_t)cg * 512 + (k0 - 768) + bh);
        } else {
            bsrc = B0 + (size_t)(col0 + bcol) * 512 + k0 + bh;
        }
        cvt8(&Bs[bcol * 40 + bh],     bsrc);
        cvt8(&Bs[bcol * 40 + bh + 8], bsrc + 8);
        __syncthreads();

        bf16x8_t af[4], bfr[4];
        const int ka = (lane >> 4) * 8;
#pragma unroll
        for (int mf = 0; mf < 4; ++mf)
            af[mf] = *(const bf16x8_t*)&As[(wm * 64 + mf * 16 + (lane & 15)) * 40 + ka];
#pragma unroll
        for (int nf = 0; nf < 4; ++nf)
            bfr[nf] = *(const bf16x8_t*)&Bs[(wn * 64 + nf * 16 + (lane & 15)) * 40 + ka];
#pragma unroll
        for (int mf = 0; mf < 4; ++mf)
#pragma unroll
            for (int nf = 0; nf < 4; ++nf)
                acc[mf][nf] = __builtin_amdgcn_mfma_f32_16x16x32_bf16(
                    af[mf], bfr[nf], acc[mf][nf], 0, 0, 0);
    }

#pragma unroll
    for (int mf = 0; mf < 4; ++mf)
#pragma unroll
        for (int nf = 0; nf < 4; ++nf) {
            const int col  = col0 + wn * 64 + nf * 16 + (lane & 15);
            const int rowb = row0 + wm * 64 + mf * 16 + ((lane >> 4) << 2);
            float bb;
            if constexpr (KIND == 0) bb = bias0[col] + bias1v[col];
            else                     bb = bias0[col];
#pragma unroll
            for (int r = 0; r < 4; ++r)
                out[(size_t)(rowb + r) * N + col] = acc[mf][nf][r] + bb;
        }
}

// ---------------------------------------------------------------------------
// small kernels
// ---------------------------------------------------------------------------
__global__ void prep_kernel(const int* __restrict__ tgt,
                            const float* __restrict__ emb,
                            const float* __restrict__ hidden,
                            short* __restrict__ x_cat)
{
    const int b = blockIdx.x, t = threadIdx.x;          // 256 threads
    const int tok = tgt[b];
    x_cat[(size_t)b * 1280 + t]             = f2bf(emb[(size_t)tok * E_ + t]);
    x_cat[(size_t)b * 1280 + 768 + t]       = f2bf(hidden[(size_t)b * H_ + t]);
    x_cat[(size_t)b * 1280 + 768 + 256 + t] = f2bf(hidden[(size_t)b * H_ + 256 + t]);
}

__global__ void softmax_kernel(const float* __restrict__ scores,
                               float* __restrict__ attn,
                               float* __restrict__ attn_out)
{
    const int b = blockIdx.x, t = threadIdx.x;          // 512 threads
    const int lane = t & 63, w = t >> 6;
    __shared__ float wred[8];
    const float val = scores[(size_t)b * S_ + t];
    float m = val;
#pragma unroll
    for (int off = 32; off; off >>= 1) m = fmaxf(m, __shfl_xor(m, off));
    if (lane == 0) wred[w] = m;
    __syncthreads();
    m = wred[0];
#pragma unroll
    for (int i = 1; i < 8; ++i) m = fmaxf(m, wred[i]);
    const float e = __expf(val - m);
    __syncthreads();
    float s = e;
#pragma unroll
    for (int off = 32; off; off >>= 1) s += __shfl_xor(s, off);
    if (lane == 0) wred[w] = s;
    __syncthreads();
    s = wred[0];
#pragma unroll
    for (int i = 1; i < 8; ++i) s += wred[i];
    const float a = e / s;
    attn[(size_t)b * S_ + t]     = a;
    attn_out[(size_t)b * S_ + t] = a;
}

__global__ void context_kernel(const float* __restrict__ attn,
                               const float* __restrict__ enc,
                               short* __restrict__ x_cat)
{
    const int b = blockIdx.x, t = threadIdx.x;          // 512 threads, one h each
    __shared__ float a_s[512];
    a_s[t] = attn[(size_t)b * S_ + t];
    __syncthreads();
    const float* ep = enc + (size_t)b * S_ * H_ + t;
    float acc0 = 0.f, acc1 = 0.f, acc2 = 0.f, acc3 = 0.f;
    for (int s = 0; s < 512; s += 8) {
        const float l0 = ep[(size_t)(s + 0) * H_];
        const float l1 = ep[(size_t)(s + 1) * H_];
        const float l2 = ep[(size_t)(s + 2) * H_];
        const float l3 = ep[(size_t)(s + 3) * H_];
        const float l4 = ep[(size_t)(s + 4) * H_];
        const float l5 = ep[(size_t)(s + 5) * H_];
        const float l6 = ep[(size_t)(s + 6) * H_];
        const float l7 = ep[(size_t)(s + 7) * H_];
        acc0 = fmaf(a_s[s + 0], l0, acc0);
        acc1 = fmaf(a_s[s + 1], l1, acc1);
        acc2 = fmaf(a_s[s + 2], l2, acc2);
        acc3 = fmaf(a_s[s + 3], l3, acc3);
        acc0 = fmaf(a_s[s + 4], l4, acc0);
        acc1 = fmaf(a_s[s + 5], l5, acc1);
        acc2 = fmaf(a_s[s + 6], l6, acc2);
        acc3 = fmaf(a_s[s + 7], l7, acc3);
    }
    x_cat[(size_t)b * 1280 + 256 + t] = f2bf((acc0 + acc1) + (acc2 + acc3));
}

__global__ void lstm_kernel(const float* __restrict__ gates,
                            const float* __restrict__ cell,
                            float* __restrict__ out_h,
                            float* __restrict__ out_c,
                            short* __restrict__ h_bf)
{
    const int b = blockIdx.x, t = threadIdx.x;          // 512 threads
    const float* g = gates + (size_t)b * 2048;
    const float gi = g[t], gf = g[512 + t], gg = g[1024 + t], go = g[1536 + t];
    const float c  = cell[(size_t)b * H_ + t];
    const float si = 1.f / (1.f + __expf(-gi));
    const float sf = 1.f / (1.f + __expf(-gf));
    const float so = 1.f / (1.f + __expf(-go));
    const float cn = sf * c + si * tanhf(gg);
    const float hn = so * tanhf(cn);
    out_h[(size_t)b * H_ + t] = hn;
    out_c[(size_t)b * H_ + t] = cn;
    h_bf[(size_t)b * H_ + t]  = f2bf(hn);
}

// ---------------------------------------------------------------------------
extern "C" void kernel_launch(void* const* d_in, const int* in_sizes, int n_in,
                              void* d_out, int out_size, void* d_ws, size_t ws_size,
                              hipStream_t stream)
{
    (void)in_sizes; (void)n_in; (void)out_size; (void)ws_size;

    const int*   tgt    = (const int*)d_in[0];
    const float* hidden = (const float*)d_in[1];
    const float* cell   = (const float*)d_in[2];
    const float* enc    = (const float*)d_in[3];
    const float* emb    = (const float*)d_in[4];
    const float* attn_W = (const float*)d_in[5];
    const float* attn_b = (const float*)d_in[6];
    const float* vv     = (const float*)d_in[7];
    const float* W_ih   = (const float*)d_in[8];
    const float* W_hh   = (const float*)d_in[9];
    const float* b_ih   = (const float*)d_in[10];
    const float* b_hh   = (const float*)d_in[11];
    const float* fc_W   = (const float*)d_in[12];
    const float* fc_b   = (const float*)d_in[13];

    float* out_pred = (float*)d_out;                       // [256][16000]
    float* out_h    = out_pred + (size_t)B_ * V_;          // [256][512]
    float* out_c    = out_h + (size_t)B_ * H_;             // [256][512]
    float* out_attn = out_c + (size_t)B_ * H_;             // [256][512]

    char*  ws     = (char*)d_ws;
    float* bias1  = (float*)ws;                            // 256*512 f32
    float* scores = bias1 + (size_t)B_ * H_;               // 131072 f32
    float* attn   = scores + (size_t)B_ * S_;              // 131072 f32
    float* gates  = attn + (size_t)B_ * S_;                // 256*2048 f32
    short* x_cat  = (short*)(gates + (size_t)B_ * 2048);   // 256*1280 bf16
    short* h_bf   = x_cat + (size_t)B_ * 1280;             // 256*512 bf16
    short* b2p    = h_bf + (size_t)B_ * H_;                // 512*512 bf16 packed

    // 0. pack W2 half into fragment-ordered bf16
    pack_w2<<<128, 256, 0, stream>>>(attn_W, b2p);
    // 1. embedding gather + h into x_cat (bf16)
    prep_kernel<<<B_, 256, 0, stream>>>(tgt, emb, hidden, x_cat);
    // 2. bias1 = h @ W1^T + attn_b
    bias1_kernel<<<128, 512, 0, stream>>>(hidden, attn_W, attn_b, bias1);
    // 3. scores[b,s] = v . tanh(enc @ W2^T + bias1[b])
    scores_gemm<<<(B_ * S_) / 128, 512, 0, stream>>>(enc, b2p, bias1, vv, scores);
    // 4. softmax over s
    softmax_kernel<<<B_, 512, 0, stream>>>(scores, attn, out_attn);
    // 5. context -> x_cat[:,256:768] (bf16)
    context_kernel<<<B_, 512, 0, stream>>>(attn, enc, x_cat);
    // 6. gates = x_cat @ [W_ih|W_hh]^T + b_ih + b_hh
    gemm_std<0><<<dim3(2, 16), 256, 0, stream>>>(x_cat, W_ih, W_hh, b_ih, b_hh, gates);
    // 7. LSTM pointwise
    lstm_kernel<<<B_, 512, 0, stream>>>(gates, cell, out_h, out_c, h_bf);
    // 8. prediction = h_new @ fc_W^T + fc_b
    gemm_std<1><<<dim3(2, 125), 256, 0, stream>>>(h_bf, fc_W, nullptr, fc_b, nullptr, out_pred);
}

// Round 3
// 282.555 us; speedup vs baseline: 1.7027x; 1.0983x over previous
//
#include <hip/hip_runtime.h>
#include <hip/hip_bf16.h>

// DecoderLSTM: B=256, S=512, H=512, E=256, V=16000
#define B_ 256
#define S_ 512
#define H_ 512
#define E_ 256
#define V_ 16000

typedef __attribute__((ext_vector_type(4))) float f32x4_t;
typedef __attribute__((ext_vector_type(8))) short bf16x8_t;

__device__ __forceinline__ short f2bf(float f) {
    union { float f; unsigned u; } v; v.f = f;
    unsigned r = v.u + 0x7fffu + ((v.u >> 16) & 1u);   // RNE
    return (short)(r >> 16);
}

__device__ __forceinline__ float bf2f(short s) {
    union { unsigned u; float f; } v; v.u = ((unsigned)(unsigned short)s) << 16;
    return v.f;
}

__device__ __forceinline__ void cvt8(short* dst, const float* src) {
    f32x4_t a = *(const f32x4_t*)src;
    f32x4_t b = *(const f32x4_t*)(src + 4);
    bf16x8_t o;
    o[0] = f2bf(a[0]); o[1] = f2bf(a[1]); o[2] = f2bf(a[2]); o[3] = f2bf(a[3]);
    o[4] = f2bf(b[0]); o[5] = f2bf(b[1]); o[6] = f2bf(b[2]); o[7] = f2bf(b[3]);
    *(bf16x8_t*)dst = o;
}

__device__ __forceinline__ bf16x8_t pack8(f32x4_t a, f32x4_t b) {
    bf16x8_t o;
    o[0] = f2bf(a[0]); o[1] = f2bf(a[1]); o[2] = f2bf(a[2]); o[3] = f2bf(a[3]);
    o[4] = f2bf(b[0]); o[5] = f2bf(b[1]); o[6] = f2bf(b[2]); o[7] = f2bf(b[3]);
    return o;
}

__device__ __forceinline__ float fast_tanh(float x) {
    float xc = fminf(8.f, fmaxf(-8.f, x));
    float e = __expf(2.f * xc);
    return (e - 1.f) / (e + 1.f);
}

// LDS chunk swizzle: row has 64 16B-chunks; interleave chunk bits + XOR row.
// Conflict-free (<=2-way) for stage-write, fragment-read, and ctx-read patterns.
__device__ __forceinline__ int physc(int c, int r) {
    return ((((c & 7) << 3) | (c >> 3)) ^ (r & 7));
}

// ---------------------------------------------------------------------------
// pack_w2: attn_W second half (W2) -> fragment-ordered bf16 for 64-col waves.
// chunk c = ((kk*8 + wn)*4 + nf)*64 + lane holds 8 bf16 of
//   W2[col = wn*64+nf*16+(lane&15)][k = kk*32+(lane>>4)*8 + j]
// ---------------------------------------------------------------------------
__global__ void pack_w2(const float* __restrict__ attn_W, short* __restrict__ Bp)
{
    const int c    = blockIdx.x * 256 + threadIdx.x;       // 32768 chunks
    const int lane = c & 63;
    const int nf   = (c >> 6) & 3;
    const int wn   = (c >> 8) & 7;
    const int kk   = c >> 11;                              // 0..15
    const int col  = wn * 64 + nf * 16 + (lane & 15);
    const int k    = kk * 32 + (lane >> 4) * 8;
    cvt8(Bp + (size_t)c * 8, attn_W + (size_t)col * (2 * H_) + H_ + k);
}

// ---------------------------------------------------------------------------
// bias1: h @ W1^T + attn_b.  128 blocks x 512 thr, 2 batches per block.
// ---------------------------------------------------------------------------
__global__ void bias1_kernel(const float* __restrict__ hidden,
                             const float* __restrict__ attn_W,
                             const float* __restrict__ attn_b,
                             float* __restrict__ bias1)
{
    const int t  = threadIdx.x;                // output col
    const int b0 = blockIdx.x * 2;
    __shared__ float h_s[2][512];
    h_s[0][t] = hidden[(size_t)b0 * H_ + t];
    h_s[1][t] = hidden[(size_t)(b0 + 1) * H_ + t];
    __syncthreads();
    const float* wrow = attn_W + (size_t)t * (2 * H_);     // W1 part: cols 0..511
    float a0 = 0.f, a1 = 0.f;
#pragma unroll 4
    for (int k = 0; k < 512; k += 4) {
        f32x4_t wv = *(const f32x4_t*)(wrow + k);
        a0 = fmaf(wv[0], h_s[0][k],     a0);
        a0 = fmaf(wv[1], h_s[0][k + 1], a0);
        a0 = fmaf(wv[2], h_s[0][k + 2], a0);
        a0 = fmaf(wv[3], h_s[0][k + 3], a0);
        a1 = fmaf(wv[0], h_s[1][k],     a1);
        a1 = fmaf(wv[1], h_s[1][k + 1], a1);
        a1 = fmaf(wv[2], h_s[1][k + 2], a1);
        a1 = fmaf(wv[3], h_s[1][k + 3], a1);
    }
    const float bb = attn_b[t];
    bias1[(size_t)b0 * H_ + t]       = a0 + bb;
    bias1[(size_t)(b0 + 1) * H_ + t] = a1 + bb;
}

// ---------------------------------------------------------------------------
// fused_attn: one block per batch b. Streams enc[b] (512x512 f32) ONCE:
//   per 64-row s-tile: stage->bf16 LDS (dbuf, swizzled); MFMA energy GEMM
//   (8 waves x 64 cols each); tanh+v reduce -> e_s = exp(score); context
//   accumulated in registers weighted by e_s. No max subtraction needed:
//   |score| <= sum|v| <= 22.6 -> exp fits f32 easily.
// Outputs: out_attn[b][512], x_cat ctx slice (bf16).
// ---------------------------------------------------------------------------
__global__ __launch_bounds__(512, 2)
void fused_attn(const float* __restrict__ enc,
                const short* __restrict__ Bp,
                const float* __restrict__ bias1,
                const float* __restrict__ vvec,
                float* __restrict__ out_attn,
                short* __restrict__ x_cat)
{
    __shared__ short buf[2][64 * 512];       // 2 x 64KB, swizzled chunks
    __shared__ float e_all[512];
    __shared__ float red[64][8];
    __shared__ float bias_s[512];
    __shared__ float v_s[512];
    __shared__ float ctxp[8][512];
    __shared__ float wred[8];
    __shared__ float l_sh;

    const int t    = threadIdx.x;
    const int lane = t & 63;
    const int w    = t >> 6;                 // wave id = col group 0..7
    const int b    = blockIdx.x;

    bias_s[t] = bias1[(size_t)b * H_ + t];
    v_s[t]    = vvec[t];

    // staging assignment: row srow (0..63), col group scg (64 cols)
    const int srow = t >> 3;
    const int scg  = t & 7;
    const float* gbase = enc + ((size_t)b * S_ + srow) * H_ + scg * 64;

    // ctx assignment: rows r0+8i, 16B chunk c (cols 8c..8c+7)
    const int r0 = t & 7;
    const int cc = t >> 3;
    float acc8[8];
#pragma unroll
    for (int j = 0; j < 8; ++j) acc8[j] = 0.f;

    // prologue: stage tile 0 into buf[0]
    {
        short* d = &buf[0][srow * 512];
#pragma unroll
        for (int i = 0; i < 8; ++i) {
            f32x4_t a = *(const f32x4_t*)(gbase + i * 8);
            f32x4_t c = *(const f32x4_t*)(gbase + i * 8 + 4);
            *(bf16x8_t*)&d[physc(scg * 8 + i, srow) * 8] = pack8(a, c);
        }
    }
    __syncthreads();

    int cur = 0;
    for (int tile = 0; tile < 8; ++tile) {
        // issue next-tile loads early (HBM latency hides under GEMM)
        f32x4_t st[16];
        if (tile < 7) {
            const float* gp = gbase + (size_t)(tile + 1) * 64 * H_;
#pragma unroll
            for (int j = 0; j < 16; ++j) st[j] = *(const f32x4_t*)(gp + j * 4);
        }

        // ---- energy GEMM on buf[cur]: 64 rows x 64 cols (this wave) x K=512
        f32x4_t acc[4][4];
#pragma unroll
        for (int mf = 0; mf < 4; ++mf)
#pragma unroll
            for (int nf = 0; nf < 4; ++nf)
                acc[mf][nf] = (f32x4_t){0.f, 0.f, 0.f, 0.f};

        const short* bufc = buf[cur];
#pragma unroll 4
        for (int kk = 0; kk < 16; ++kk) {
            const short* bb = Bp + ((size_t)((kk * 8 + w) * 256 + lane)) * 8;
            bf16x8_t bfr[4], af[4];
#pragma unroll
            for (int nf = 0; nf < 4; ++nf)
                bfr[nf] = *(const bf16x8_t*)(bb + nf * 512);
            const int cpr = kk * 4 + (lane >> 4);
#pragma unroll
            for (int mf = 0; mf < 4; ++mf) {
                const int rl = mf * 16 + (lane & 15);
                af[mf] = *(const bf16x8_t*)&bufc[rl * 512 + physc(cpr, rl) * 8];
            }
#pragma unroll
            for (int mf = 0; mf < 4; ++mf)
#pragma unroll
                for (int nf = 0; nf < 4; ++nf)
                    acc[mf][nf] = __builtin_amdgcn_mfma_f32_16x16x32_bf16(
                        af[mf], bfr[nf], acc[mf][nf], 0, 0, 0);
        }

        // ---- epilogue: per-wave partial score = sum over its 64 cols
        float part[16];
#pragma unroll
        for (int i = 0; i < 16; ++i) part[i] = 0.f;
#pragma unroll
        for (int nf = 0; nf < 4; ++nf) {
            const int col = w * 64 + nf * 16 + (lane & 15);
            const float bb = bias_s[col];
            const float vl = v_s[col];
#pragma unroll
            for (int mf = 0; mf < 4; ++mf)
#pragma unroll
                for (int r = 0; r < 4; ++r)
                    part[mf * 4 + r] += vl * fast_tanh(acc[mf][nf][r] + bb);
        }
#pragma unroll
        for (int i = 0; i < 16; ++i) {
            float p = part[i];
            p += __shfl_xor(p, 1);
            p += __shfl_xor(p, 2);
            p += __shfl_xor(p, 4);
            p += __shfl_xor(p, 8);
            part[i] = p;
        }
        if ((lane & 15) == 0) {
#pragma unroll
            for (int mf = 0; mf < 4; ++mf)
#pragma unroll
                for (int r = 0; r < 4; ++r)
                    red[mf * 16 + ((lane >> 4) << 2) + r][w] = part[mf * 4 + r];
        }
        __syncthreads();

        // scores -> e (64 threads), others write next tile to buf[cur^1]
        if (t < 64) {
            float s = red[t][0] + red[t][1] + red[t][2] + red[t][3]
                    + red[t][4] + red[t][5] + red[t][6] + red[t][7];
            e_all[tile * 64 + t] = __expf(s);
        }
        if (tile < 7) {
            short* d = &buf[cur ^ 1][srow * 512];
#pragma unroll
            for (int i = 0; i < 8; ++i)
                *(bf16x8_t*)&d[physc(scg * 8 + i, srow) * 8] = pack8(st[2 * i], st[2 * i + 1]);
        }
        __syncthreads();

        // ---- context accumulate from buf[cur] (rows r0+8i, cols 8cc..8cc+7)
#pragma unroll
        for (int i = 0; i < 8; ++i) {
            const int r  = i * 8 + r0;
            const float e = e_all[tile * 64 + r];
            bf16x8_t ch = *(const bf16x8_t*)&bufc[r * 512 + physc(cc, r) * 8];
#pragma unroll
            for (int j = 0; j < 8; ++j)
                acc8[j] = fmaf(e, bf2f(ch[j]), acc8[j]);
        }
        // no barrier needed: next iter's buf[cur] writes are after its own barrier
        cur ^= 1;
    }

    // ---- finalize: l = sum(e), attn out, ctx out
#pragma unroll
    for (int j = 0; j < 8; ++j) ctxp[r0][cc * 8 + j] = acc8[j];
    float ev = e_all[t];
    float sv = ev;
#pragma unroll
    for (int off = 32; off; off >>= 1) sv += __shfl_xor(sv, off);
    if (lane == 0) wred[w] = sv;
    __syncthreads();
    if (t == 0) {
        l_sh = wred[0] + wred[1] + wred[2] + wred[3]
             + wred[4] + wred[5] + wred[6] + wred[7];
    }
    __syncthreads();
    const float linv = 1.f / l_sh;
    out_attn[(size_t)b * S_ + t] = ev * linv;
    float cs = 0.f;
#pragma unroll
    for (int g = 0; g < 8; ++g) cs += ctxp[g][t];
    x_cat[(size_t)b * 1280 + 256 + t] = f2bf(cs * linv);
}

// ---------------------------------------------------------------------------
// gemm_std: BM=128, BN=128, BK=32, 4 waves (256 thr). A is pre-converted bf16.
// KIND 0 (gates): K=1280, N=2048, B = [W_ih | W_hh] rows, bias = b_ih+b_hh
// KIND 1 (pred):  K=512,  N=16000, B = fc_W rows,        bias = fc_b
// ---------------------------------------------------------------------------
template<int KIND>
__global__ __launch_bounds__(256, 2)
void gemm_std(const short* __restrict__ Abf,
              const float* __restrict__ B0,
              const float* __restrict__ B1,
              const float* __restrict__ bias0,
              const float* __restrict__ bias1v,
              float* __restrict__ out)
{
    constexpr int K = (KIND == 0) ? 1280 : 512;
    constexpr int N = (KIND == 0) ? 2048 : 16000;

    __shared__ short As[128 * 40];
    __shared__ short Bs[128 * 40];

    const int t    = threadIdx.x;
    const int lane = t & 63;
    const int w    = t >> 6;
    const int wm   = w >> 1;
    const int wn   = w & 1;
    const int row0 = blockIdx.x * 128;
    const int col0 = blockIdx.y * 128;

    f32x4_t acc[4][4];
#pragma unroll
    for (int i = 0; i < 4; ++i)
#pragma unroll
        for (int j = 0; j < 4; ++j)
            acc[i][j] = (f32x4_t){0.f, 0.f, 0.f, 0.f};

    const int arow = t >> 1, ah = (t & 1) * 16;
    const int bcol = t >> 1, bh = (t & 1) * 16;

    for (int ks = 0; ks < K / 32; ++ks) {
        const int k0 = ks * 32;
        __syncthreads();
        const short* asrc = Abf + (size_t)(row0 + arow) * K + k0 + ah;
        *(bf16x8_t*)&As[arow * 40 + ah]     = *(const bf16x8_t*)asrc;
        *(bf16x8_t*)&As[arow * 40 + ah + 8] = *(const bf16x8_t*)(asrc + 8);
        const float* bsrc;
        if constexpr (KIND == 0) {
            const int cg = col0 + bcol;
            bsrc = (k0 < 768) ? (B0 + (size_t)cg * 768 + k0 + bh)
                              : (B1 + (size_t)cg * 512 + (k0 - 768) + bh);
        } else {
            bsrc = B0 + (size_t)(col0 + bcol) * 512 + k0 + bh;
        }
        cvt8(&Bs[bcol * 40 + bh],     bsrc);
        cvt8(&Bs[bcol * 40 + bh + 8], bsrc + 8);
        __syncthreads();

        bf16x8_t af[4], bfr[4];
        const int ka = (lane >> 4) * 8;
#pragma unroll
        for (int mf = 0; mf < 4; ++mf)
            af[mf] = *(const bf16x8_t*)&As[(wm * 64 + mf * 16 + (lane & 15)) * 40 + ka];
#pragma unroll
        for (int nf = 0; nf < 4; ++nf)
            bfr[nf] = *(const bf16x8_t*)&Bs[(wn * 64 + nf * 16 + (lane & 15)) * 40 + ka];
#pragma unroll
        for (int mf = 0; mf < 4; ++mf)
#pragma unroll
            for (int nf = 0; nf < 4; ++nf)
                acc[mf][nf] = __builtin_amdgcn_mfma_f32_16x16x32_bf16(
                    af[mf], bfr[nf], acc[mf][nf], 0, 0, 0);
    }

#pragma unroll
    for (int mf = 0; mf < 4; ++mf)
#pragma unroll
        for (int nf = 0; nf < 4; ++nf) {
            const int col  = col0 + wn * 64 + nf * 16 + (lane & 15);
            const int rowb = row0 + wm * 64 + mf * 16 + ((lane >> 4) << 2);
            float bb;
            if constexpr (KIND == 0) bb = bias0[col] + bias1v[col];
            else                     bb = bias0[col];
#pragma unroll
            for (int r = 0; r < 4; ++r)
                out[(size_t)(rowb + r) * N + col] = acc[mf][nf][r] + bb;
        }
}

// ---------------------------------------------------------------------------
// small kernels
// ---------------------------------------------------------------------------
__global__ void prep_kernel(const int* __restrict__ tgt,
                            const float* __restrict__ emb,
                            const float* __restrict__ hidden,
                            short* __restrict__ x_cat)
{
    const int b = blockIdx.x, t = threadIdx.x;          // 256 threads
    const int tok = tgt[b];
    x_cat[(size_t)b * 1280 + t]             = f2bf(emb[(size_t)tok * E_ + t]);
    x_cat[(size_t)b * 1280 + 768 + t]       = f2bf(hidden[(size_t)b * H_ + t]);
    x_cat[(size_t)b * 1280 + 768 + 256 + t] = f2bf(hidden[(size_t)b * H_ + 256 + t]);
}

__global__ void lstm_kernel(const float* __restrict__ gates,
                            const float* __restrict__ cell,
                            float* __restrict__ out_h,
                            float* __restrict__ out_c,
                            short* __restrict__ h_bf)
{
    const int b = blockIdx.x, t = threadIdx.x;          // 512 threads
    const float* g = gates + (size_t)b * 2048;
    const float gi = g[t], gf = g[512 + t], gg = g[1024 + t], go = g[1536 + t];
    const float c  = cell[(size_t)b * H_ + t];
    const float si = 1.f / (1.f + __expf(-gi));
    const float sf = 1.f / (1.f + __expf(-gf));
    const float so = 1.f / (1.f + __expf(-go));
    const float cn = sf * c + si * tanhf(gg);
    const float hn = so * tanhf(cn);
    out_h[(size_t)b * H_ + t] = hn;
    out_c[(size_t)b * H_ + t] = cn;
    h_bf[(size_t)b * H_ + t]  = f2bf(hn);
}

// ---------------------------------------------------------------------------
extern "C" void kernel_launch(void* const* d_in, const int* in_sizes, int n_in,
                              void* d_out, int out_size, void* d_ws, size_t ws_size,
                              hipStream_t stream)
{
    (void)in_sizes; (void)n_in; (void)out_size; (void)ws_size;

    const int*   tgt    = (const int*)d_in[0];
    const float* hidden = (const float*)d_in[1];
    const float* cell   = (const float*)d_in[2];
    const float* enc    = (const float*)d_in[3];
    const float* emb    = (const float*)d_in[4];
    const float* attn_W = (const float*)d_in[5];
    const float* attn_b = (const float*)d_in[6];
    const float* vv     = (const float*)d_in[7];
    const float* W_ih   = (const float*)d_in[8];
    const float* W_hh   = (const float*)d_in[9];
    const float* b_ih   = (const float*)d_in[10];
    const float* b_hh   = (const float*)d_in[11];
    const float* fc_W   = (const float*)d_in[12];
    const float* fc_b   = (const float*)d_in[13];

    float* out_pred = (float*)d_out;                       // [256][16000]
    float* out_h    = out_pred + (size_t)B_ * V_;          // [256][512]
    float* out_c    = out_h + (size_t)B_ * H_;             // [256][512]
    float* out_attn = out_c + (size_t)B_ * H_;             // [256][512]

    char*  ws     = (char*)d_ws;
    float* bias1  = (float*)ws;                            // 256*512 f32
    float* gates  = bias1 + (size_t)B_ * H_;               // 256*2048 f32
    short* x_cat  = (short*)(gates + (size_t)B_ * 2048);   // 256*1280 bf16
    short* h_bf   = x_cat + (size_t)B_ * 1280;             // 256*512 bf16
    short* b2p    = h_bf + (size_t)B_ * H_;                // 512*512 bf16 packed

    // 0. pack W2 half into fragment-ordered bf16
    pack_w2<<<128, 256, 0, stream>>>(attn_W, b2p);
    // 1. embedding gather + h into x_cat (bf16)
    prep_kernel<<<B_, 256, 0, stream>>>(tgt, emb, hidden, x_cat);
    // 2. bias1 = h @ W1^T + attn_b
    bias1_kernel<<<128, 512, 0, stream>>>(hidden, attn_W, attn_b, bias1);
    // 3. fused attention: scores + softmax + context, enc read once
    fused_attn<<<B_, 512, 0, stream>>>(enc, b2p, bias1, vv, out_attn, x_cat);
    // 4. gates = x_cat @ [W_ih|W_hh]^T + b_ih + b_hh
    gemm_std<0><<<dim3(2, 16), 256, 0, stream>>>(x_cat, W_ih, W_hh, b_ih, b_hh, gates);
    // 5. LSTM pointwise
    lstm_kernel<<<B_, 512, 0, stream>>>(gates, cell, out_h, out_c, h_bf);
    // 6. prediction = h_new @ fc_W^T + fc_b
    gemm_std<1><<<dim3(2, 125), 256, 0, stream>>>(h_bf, fc_W, nullptr, fc_b, nullptr, out_pred);
}